// Round 1
// baseline (238.582 us; speedup 1.0000x reference)
//
#include <hip/hip_runtime.h>
#include <math.h>

// x: (16, 512, 512, 8) float32 NHWC. float4 granule index:
//   f4idx = ((n*512 + h)*512 + w)*2 + c4,  c4 in {0,1}
// Thread owns a column (n, w, c4) and produces HPT=8 consecutive h outputs.
//
// ROLLING 3-ROW PIPELINE (v2): instead of holding all 30 window loads live
// (which pushed VGPR to 72, just past the 64-reg occupancy cliff -> only
// 4 waves/SIMD), each unrolled step loads ONE row (a,b,c), computes the three
// per-mask-row horizontal maxes R0/R1/R2, and emits output s=r-2 from
// max(R0[row s], R1[row s+1], R2[row s+2]). Peak liveness ~56 VGPRs.
// __launch_bounds__(256, 8) pins 8 blocks/CU (8 waves/SIMD, VGPR<=64).

constexpr int Hdim = 512;
constexpr int Wdim = 512;
constexpr int HPT  = 8;
constexpr int ROWS = HPT + 2;
constexpr int ROW  = Wdim * 2;   // f4 stride between rows

__device__ __forceinline__ float4 f4max(float4 a, float4 b) {
    return make_float4(fmaxf(a.x,b.x), fmaxf(a.y,b.y), fmaxf(a.z,b.z), fmaxf(a.w,b.w));
}

__global__ __launch_bounds__(256, 8) void nms_kernel(
    const float4* __restrict__ x,
    const unsigned char* __restrict__ mask_bytes,
    float4* __restrict__ out)
{
    // ---- Decode 3x3 boolean mask robustly (int32 vs 1-byte bool layout).
    const int* mi = (const int*)mask_bytes;
    bool intlay = true;
    #pragma unroll
    for (int i = 0; i < 9; ++i) { int v = mi[i]; intlay = intlay && (v == 0 || v == 1); }
    bool m[9];
    #pragma unroll
    for (int i = 0; i < 9; ++i) m[i] = intlay ? (mi[i] != 0) : (mask_bytes[i] != 0);

    int gid = blockIdx.x * blockDim.x + threadIdx.x;
    int c4 = gid & 1;
    int w  = (gid >> 1) & (Wdim - 1);
    int hg = (gid >> 10) & 63;          // 512/HPT = 64 h-groups; uniform per block
    int n  = gid >> 16;
    int h0 = hg * HPT;

    const float4 NEG = make_float4(-INFINITY, -INFINITY, -INFINITY, -INFINITY);
    bool aok = (w > 0), cok = (w < Wdim - 1);
    int ao = aok ? -2 : 0;              // clamped w-offsets (NEG-fixed per row)
    int co = cok ?  2 : 0;
    bool topclamp = (h0 == 0);            // block-uniform
    bool botclamp = (h0 + HPT == Hdim);   // block-uniform

    int base = ((n * Hdim + h0) * Wdim + w) * 2 + c4;

    // Block-uniform row offset (rows 1..ROWS-2 are always in-range).
    auto rowoff = [&](int r) -> int {
        int roff = (r - 1) * ROW;
        if (r == 0 && topclamp) roff = 0;                    // h=-1 -> clamp (value unused)
        if (r == ROWS - 1 && botclamp) roff = (HPT - 1) * ROW; // h=512 -> clamp (value unused)
        return roff;
    };

    // ---- Prime the pipeline with row 0.
    float4 A, Bv, C, pA, pB, pC;
    {
        int rb = base + rowoff(0);
        A = x[rb + ao]; Bv = x[rb]; C = x[rb + co];
    }

    // Histories: R0 two rows back, R0/R1/center one row back.
    float4 R0p2 = NEG, R0p1 = NEG, R1p1 = NEG, CTp1 = NEG;

    #pragma unroll
    for (int r = 0; r < ROWS; ++r) {
        // Prefetch next row so its latency hides under this row's VALU.
        if (r < ROWS - 1) {
            int rb = base + rowoff(r + 1);
            pA = x[rb + ao]; pB = x[rb]; pC = x[rb + co];
        }

        // w-edge fixup (per-lane, 2 lanes per 512)
        float4 a = A, b = Bv, c = C;
        a.x = aok ? a.x : -INFINITY; a.y = aok ? a.y : -INFINITY;
        a.z = aok ? a.z : -INFINITY; a.w = aok ? a.w : -INFINITY;
        c.x = cok ? c.x : -INFINITY; c.y = cok ? c.y : -INFINITY;
        c.z = cok ? c.z : -INFINITY; c.w = cok ? c.w : -INFINITY;

        // Horizontal masked maxes for this row in each window-row role.
        float4 R0 = NEG, R1 = NEG, R2 = NEG;
        if (m[0]) R0 = f4max(R0, a);
        if (m[1]) R0 = f4max(R0, b);
        if (m[2]) R0 = f4max(R0, c);
        if (m[3]) R1 = f4max(R1, a);
        if (m[4]) R1 = f4max(R1, b);
        if (m[5]) R1 = f4max(R1, c);
        if (m[6]) R2 = f4max(R2, a);
        if (m[7]) R2 = f4max(R2, b);
        if (m[8]) R2 = f4max(R2, c);
        if (r == 0 && topclamp)        R0 = NEG;   // row h=-1 doesn't exist
        if (r == ROWS - 1 && botclamp) R2 = NEG;   // row h=512 doesn't exist

        // Emit output s = r-2: window rows are (s, s+1, s+2) = (r-2, r-1, r).
        if (r >= 2) {
            int s = r - 2;
            float4 mm = f4max(f4max(R0p2, R1p1), R2);
            float4 ctr = CTp1;
            float4 o;
            o.x = (ctr.x > mm.x) ? ctr.x : 0.0f;
            o.y = (ctr.y > mm.y) ? ctr.y : 0.0f;
            o.z = (ctr.z > mm.z) ? ctr.z : 0.0f;
            o.w = (ctr.w > mm.w) ? ctr.w : 0.0f;
            out[base + s * ROW] = o;
        }

        // Shift pipeline state.
        R0p2 = R0p1; R0p1 = R0; R1p1 = R1; CTp1 = Bv;
        A = pA; Bv = pB; C = pC;
    }
}

extern "C" void kernel_launch(void* const* d_in, const int* in_sizes, int n_in,
                              void* d_out, int out_size, void* d_ws, size_t ws_size,
                              hipStream_t stream) {
    const float4* x = (const float4*)d_in[0];
    const unsigned char* mask = (const unsigned char*)d_in[1];
    float4* out = (float4*)d_out;

    // total threads = 16 * (512/HPT) * 512 * 2 = 1,048,576
    int total = 16 * (Hdim / HPT) * Wdim * 2;
    int block = 256;
    int grid = total / block;   // 4096
    nms_kernel<<<grid, block, 0, stream>>>(x, mask, out);
}